// Round 5
// baseline (742.258 us; speedup 1.0000x reference)
//
#include <hip/hip_runtime.h>

#define NN 512
#define MROWS (NN*NN)        // 262144

typedef __attribute__((ext_vector_type(8))) short short8;
typedef __attribute__((ext_vector_type(16))) float floatx16;

__device__ __forceinline__ unsigned f2bf(float f) {
    union { float f; unsigned u; } x; x.f = f;
    unsigned r = x.u + 0x7fffu + ((x.u >> 16) & 1u);
    return r >> 16;
}

__device__ __forceinline__ floatx16 zero16() {
    floatx16 z;
    #pragma unroll
    for (int i = 0; i < 16; ++i) z[i] = 0.f;
    return z;
}

// ---------------- pre: proj (blocks 0..1023) + weight fragment swizzle (1024..1535) ----
// frag1[((h*4+t)*8+kk)*512 + l*8 + j] = bf16 Wb[(h*128+t*32+(l&31))*128 + kk*16 + (l>>5)*8 + j]
// frag2[(((h*4+t)*2+sg)*4+u)*512 + l*8 + j] = bf16 Wbo[(u*32+(l&31))*512 + h*128+t*32+sg*16+(l>>5)*8 + j]
__global__ __launch_bounds__(256) void pre_kernel(
    const float* __restrict__ q, const float* __restrict__ k,
    const float* __restrict__ Wq, const float* __restrict__ bq,
    const float* __restrict__ Wk, const float* __restrict__ bk,
    float* __restrict__ pq, float* __restrict__ pk,
    const float* __restrict__ Wb, const float* __restrict__ Wbo,
    unsigned short* __restrict__ wfrag)
{
    int b = blockIdx.x;
    int tid = threadIdx.x;
    if (b >= 1024) {
        int o = (b - 1024) * 256 + tid;          // 131072 fragment elements
        float v;
        if (o < 65536) {
            int j = o & 7, l = (o >> 3) & 63, kk = (o >> 9) & 7, t = (o >> 12) & 3, h = o >> 14;
            int l31 = l & 31, qh = l >> 5;
            v = Wb[(h*128 + t*32 + l31)*128 + kk*16 + qh*8 + j];
        } else {
            int o2 = o - 65536;
            int j = o2 & 7, l = (o2 >> 3) & 63, u = (o2 >> 9) & 3, sg = (o2 >> 11) & 1,
                t = (o2 >> 12) & 3, h = o2 >> 14;
            int l31 = l & 31, qh = l >> 5;
            v = Wbo[(u*32 + l31)*512 + h*128 + t*32 + sg*16 + qh*8 + j];
        }
        wfrag[o] = (unsigned short)f2bf(v);
        return;
    }
    __shared__ float xs[64];
    int n = b & 511;
    int is_k = b >> 9;
    const float* x  = is_k ? k  : q;
    const float* W  = is_k ? Wk : Wq;
    const float* bi = is_k ? bk : bq;
    float* out      = is_k ? pk : pq;
    if (tid < 16)
        reinterpret_cast<float4*>(xs)[tid] = reinterpret_cast<const float4*>(x + n*64)[tid];
    __syncthreads();
    #pragma unroll
    for (int jj = 0; jj < 2; ++jj) {
        int j = jj*256 + tid;
        const float4* wr = reinterpret_cast<const float4*>(W + j*64);
        float acc = bi[j];
        #pragma unroll
        for (int c = 0; c < 16; ++c) {
            float4 w4 = wr[c];
            float4 x4 = reinterpret_cast<const float4*>(xs)[c];
            acc += x4.x*w4.x + x4.y*w4.y + x4.z*w4.z + x4.w*w4.w;
        }
        out[n*512 + j] = acc;
    }
}

// ---------------- fused bias path v4: frag-ordered weights, m=64/wave, no main-loop barriers --
__global__ __launch_bounds__(256, 2) void bias_kernel(
    const float* __restrict__ bias, const unsigned short* __restrict__ frag1,
    const float* __restrict__ bb, const unsigned short* __restrict__ frag2,
    const float* __restrict__ bbo, float* __restrict__ bias_out,
    float* __restrict__ diffs)
{
    __shared__ __align__(16) float lT[4][32*132];   // wave-private transpose slabs (67.6 KB)

    const int tid = threadIdx.x;
    const int w   = tid >> 6;
    const int l   = tid & 63;
    const int l31 = l & 31;
    const int qh  = l >> 5;
    const long row0 = (long)blockIdx.x * 256;
    const long wrow = row0 + (long)w * 64;          // wave's 64-row base

    // ---- one-time gather of bias B-fragments (bf16): bfr[ms][kk], m = l31, k = kk*16+qh*8+j
    short8 bfr[2][8];
    #pragma unroll
    for (int ms = 0; ms < 2; ++ms) {
        const float* bp = bias + (wrow + ms*32 + l31)*128 + qh*8;
        #pragma unroll
        for (int kk = 0; kk < 8; ++kk) {
            float4 f0 = *reinterpret_cast<const float4*>(bp + kk*16);
            float4 f1 = *reinterpret_cast<const float4*>(bp + kk*16 + 4);
            union { unsigned u[4]; short8 s; } pk_;
            pk_.u[0] = f2bf(f0.x) | (f2bf(f0.y) << 16);
            pk_.u[1] = f2bf(f0.z) | (f2bf(f0.w) << 16);
            pk_.u[2] = f2bf(f1.x) | (f2bf(f1.y) << 16);
            pk_.u[3] = f2bf(f1.z) | (f2bf(f1.w) << 16);
            bfr[ms][kk] = pk_.s;
        }
    }

    floatx16 acc2[4][2];
    #pragma unroll
    for (int u = 0; u < 4; ++u) { acc2[u][0] = zero16(); acc2[u][1] = zero16(); }

    const unsigned short* f1p = frag1 + l*8;
    const unsigned short* f2p = frag2 + l*8;

    #pragma unroll 1
    for (int h = 0; h < 4; ++h) {
        float dsum0 = 0.f, dsum1 = 0.f;
        #pragma unroll
        for (int t = 0; t < 4; ++t) {
            // ---- phase 1: D1[n1-tile t][m=64] = Wb_h,t . bias^T  (coalesced A, reused x2) ----
            floatx16 a1[2];
            a1[0] = zero16(); a1[1] = zero16();
            #pragma unroll
            for (int kk = 0; kk < 8; ++kk) {
                short8 afr = *reinterpret_cast<const short8*>(f1p + (((h*4 + t)*8) + kk)*512);
                a1[0] = __builtin_amdgcn_mfma_f32_32x32x16_bf16(afr, bfr[0][kk], a1[0], 0, 0, 0);
                a1[1] = __builtin_amdgcn_mfma_f32_32x32x16_bf16(afr, bfr[1][kk], a1[1], 0, 0, 0);
            }
            // ---- +bb, sumsq, pack (n1(reg)= (reg&3)+8*(reg>>2)+4*qh) ----
            unsigned pk0[8], pk1[8];
            #pragma unroll
            for (int j = 0; j < 4; ++j) {
                float4 b4 = *reinterpret_cast<const float4*>(bb + h*128 + t*32 + j*8 + qh*4);
                const float* bp = (const float*)&b4;
                float q0 = a1[0][4*j+0] + bp[0], q1 = a1[0][4*j+1] + bp[1];
                float q2 = a1[0][4*j+2] + bp[2], q3 = a1[0][4*j+3] + bp[3];
                dsum0 += q0*q0 + q1*q1 + q2*q2 + q3*q3;
                pk0[2*j]   = f2bf(q0) | (f2bf(q1) << 16);
                pk0[2*j+1] = f2bf(q2) | (f2bf(q3) << 16);
                float r0 = a1[1][4*j+0] + bp[0], r1 = a1[1][4*j+1] + bp[1];
                float r2 = a1[1][4*j+2] + bp[2], r3 = a1[1][4*j+3] + bp[3];
                dsum1 += r0*r0 + r1*r1 + r2*r2 + r3*r3;
                pk1[2*j]   = f2bf(r0) | (f2bf(r1) << 16);
                pk1[2*j+1] = f2bf(r2) | (f2bf(r3) << 16);
            }
            // ---- in-register transform -> phase2 B-operand; phase 2 (coalesced A, reused x2) --
            #pragma unroll
            for (int sg = 0; sg < 2; ++sg) {
                unsigned sA0 = qh ? pk0[4*sg]   : pk0[4*sg+2];
                unsigned sB0 = qh ? pk0[4*sg+1] : pk0[4*sg+3];
                unsigned sA1 = qh ? pk1[4*sg]   : pk1[4*sg+2];
                unsigned sB1 = qh ? pk1[4*sg+1] : pk1[4*sg+3];
                unsigned rA0 = (unsigned)__shfl_xor((int)sA0, 32);
                unsigned rB0 = (unsigned)__shfl_xor((int)sB0, 32);
                unsigned rA1 = (unsigned)__shfl_xor((int)sA1, 32);
                unsigned rB1 = (unsigned)__shfl_xor((int)sB1, 32);
                union { unsigned u[4]; short8 s; } pf0, pf1;
                pf0.u[0] = qh ? rA0 : pk0[4*sg];
                pf0.u[1] = qh ? rB0 : pk0[4*sg+1];
                pf0.u[2] = qh ? pk0[4*sg+2] : rA0;
                pf0.u[3] = qh ? pk0[4*sg+3] : rB0;
                pf1.u[0] = qh ? rA1 : pk1[4*sg];
                pf1.u[1] = qh ? rB1 : pk1[4*sg+1];
                pf1.u[2] = qh ? pk1[4*sg+2] : rA1;
                pf1.u[3] = qh ? pk1[4*sg+3] : rB1;
                #pragma unroll
                for (int u = 0; u < 4; ++u) {
                    short8 af2 = *reinterpret_cast<const short8*>(
                        f2p + ((((h*4 + t)*2 + sg)*4) + u)*512);
                    acc2[u][0] = __builtin_amdgcn_mfma_f32_32x32x16_bf16(af2, pf0.s, acc2[u][0], 0, 0, 0);
                    acc2[u][1] = __builtin_amdgcn_mfma_f32_32x32x16_bf16(af2, pf1.s, acc2[u][1], 0, 0, 0);
                }
            }
        }
        dsum0 += __shfl_xor(dsum0, 32);
        dsum1 += __shfl_xor(dsum1, 32);
        if (qh == 0) {
            diffs[(long)h*MROWS + wrow + l31]      = sqrtf(dsum0);
            diffs[(long)h*MROWS + wrow + 32 + l31] = sqrtf(dsum1);
        }
    }

    // ---- epilogue: +bbo, mish, wave-private LDS transpose, coalesced 1KB stores ----
    float* slab = lT[w];
    #pragma unroll 1
    for (int ms = 0; ms < 2; ++ms) {
        #pragma unroll
        for (int u = 0; u < 4; ++u) {
            #pragma unroll
            for (int g = 0; g < 4; ++g) {
                float4 b4 = *reinterpret_cast<const float4*>(bbo + u*32 + g*8 + qh*4);
                const float* bp = (const float*)&b4;
                float4 o;
                float* op = (float*)&o;
                #pragma unroll
                for (int r = 0; r < 4; ++r) {
                    float x = acc2[u][ms][g*4 + r] + bp[r];
                    float e = __expf(x);
                    float un = 1.f + e, u2 = un*un;
                    op[r] = (x > 15.f) ? x : x * (u2 - 1.f) / (u2 + 1.f);
                }
                *reinterpret_cast<float4*>(&slab[l31*132 + u*32 + g*8 + qh*4]) = o;
            }
        }
        #pragma unroll
        for (int i = 0; i < 16; ++i) {
            int flat = i*256 + l*4;
            int r = flat >> 7, c = flat & 127;
            *reinterpret_cast<float4*>(bias_out + (wrow + ms*32 + r)*128 + c) =
                *reinterpret_cast<const float4*>(&slab[r*132 + c]);
        }
    }
}

// ---------------- QK^T logits (in-place over diffs): logits = pq.pk/sqrt(D) + diffs ----------------
__global__ __launch_bounds__(256) void qk_kernel(
    const float* __restrict__ pq, const float* __restrict__ pk,
    float* __restrict__ logits)
{
    __shared__ float A[64*128];
    __shared__ float BT[128*64];
    int blk = blockIdx.x;
    int kt = blk & 7, h = (blk >> 3) & 3, qt = blk >> 5;
    int tid = threadIdx.x;

    #pragma unroll
    for (int i = 0; i < 8; ++i) {
        int flat = i*1024 + tid*4;
        int r = flat >> 7, c = flat & 127;
        *reinterpret_cast<float4*>(&A[flat]) =
            *reinterpret_cast<const float4*>(pq + (size_t)(qt*64 + r)*512 + h*128 + c);
    }
    {
        int kk = tid & 63, g = tid >> 6;
        #pragma unroll
        for (int i = 0; i < 8; ++i) {
            int d0 = g*32 + i*4;
            float4 vv = *reinterpret_cast<const float4*>(pk + (size_t)(kt*64 + kk)*512 + h*128 + d0);
            BT[(d0+0)*64 + kk] = vv.x;
            BT[(d0+1)*64 + kk] = vv.y;
            BT[(d0+2)*64 + kk] = vv.z;
            BT[(d0+3)*64 + kk] = vv.w;
        }
    }
    __syncthreads();

    int qg = tid >> 4, kg = tid & 15;
    int qs = qg*4, ks = kg*4;
    float acc[4][4] = {};
    for (int d = 0; d < 128; d += 4) {
        float a_[4][4], b_[4][4];
        #pragma unroll
        for (int i = 0; i < 4; ++i) {
            float4 av = *reinterpret_cast<const float4*>(&A[(qs+i)*128 + d]);
            a_[i][0] = av.x; a_[i][1] = av.y; a_[i][2] = av.z; a_[i][3] = av.w;
        }
        #pragma unroll
        for (int dd = 0; dd < 4; ++dd) {
            float4 bv = *reinterpret_cast<const float4*>(&BT[(d+dd)*64 + ks]);
            b_[dd][0] = bv.x; b_[dd][1] = bv.y; b_[dd][2] = bv.z; b_[dd][3] = bv.w;
        }
        #pragma unroll
        for (int i = 0; i < 4; ++i)
            #pragma unroll
            for (int j = 0; j < 4; ++j)
                acc[i][j] += a_[i][0]*b_[0][j] + a_[i][1]*b_[1][j]
                           + a_[i][2]*b_[2][j] + a_[i][3]*b_[3][j];
    }

    const float scale = 0.088388347648318447f;   // 1/sqrt(128)
    #pragma unroll
    for (int i = 0; i < 4; ++i) {
        size_t off = (size_t)h*MROWS + (size_t)(qt*64 + qs + i)*512 + kt*64 + ks;
        float4* p = reinterpret_cast<float4*>(logits + off);
        float4 dv = *p;
        dv.x = fmaf(acc[i][0], scale, dv.x);
        dv.y = fmaf(acc[i][1], scale, dv.y);
        dv.z = fmaf(acc[i][2], scale, dv.z);
        dv.w = fmaf(acc[i][3], scale, dv.w);
        *p = dv;
    }
}

// ---------------- softmax + v reduction -> vals_mean ----------------
__global__ __launch_bounds__(256) void attnval_kernel(
    const float* __restrict__ logits, const float* __restrict__ v,
    float* __restrict__ vmean)
{
    __shared__ float red[32];
    int qrow = blockIdx.x, tid = threadIdx.x;
    int wid = tid >> 6;
    float vsum = 0.f;
    float v0 = v[tid], v1 = v[tid + 256];
    for (int h = 0; h < 4; ++h) {
        const float* lr = logits + (size_t)h*MROWS + (size_t)qrow*512;
        float l0 = lr[tid], l1 = lr[tid + 256];
        float m = fmaxf(l0, l1);
        #pragma unroll
        for (int o = 1; o < 64; o <<= 1) m = fmaxf(m, __shfl_xor(m, o));
        if ((tid & 63) == 0) red[wid] = m;
        __syncthreads();
        m = fmaxf(fmaxf(red[0], red[1]), fmaxf(red[2], red[3]));
        float e0 = __expf(l0 - m), e1 = __expf(l1 - m);
        float s = e0 + e1;
        float sv = e0*v0 + e1*v1;
        #pragma unroll
        for (int o = 1; o < 64; o <<= 1) { s += __shfl_xor(s, o); sv += __shfl_xor(sv, o); }
        __syncthreads();
        if ((tid & 63) == 0) { red[8 + wid] = s; red[16 + wid] = sv; }
        __syncthreads();
        float S  = red[8]  + red[9]  + red[10] + red[11];
        float SV = red[16] + red[17] + red[18] + red[19];
        vsum += SV / S;
        __syncthreads();
    }
    if (tid == 0) vmean[qrow] = vsum * 0.25f;
}

// ---------------- q_new/k_new: layernorm(x + mish(p_flat @ W.T + b)) ----------------
__global__ __launch_bounds__(256) void qkout_kernel(
    const float* __restrict__ p, const float* __restrict__ x,
    const float* __restrict__ W, const float* __restrict__ bo,
    const float* __restrict__ g, const float* __restrict__ be,
    float* __restrict__ out)
{
    __shared__ float pr[512];
    __shared__ float red[256];
    int n = blockIdx.x, tid = threadIdx.x;
    if (tid < 128)
        reinterpret_cast<float4*>(pr)[tid] = reinterpret_cast<const float4*>(p + (size_t)n*512)[tid];
    __syncthreads();
    int o = tid >> 2, part = tid & 3;
    const float4* wr = reinterpret_cast<const float4*>(W + o*512 + part*128);
    float acc = 0.f;
    #pragma unroll
    for (int c = 0; c < 32; ++c) {
        float4 w4 = wr[c];
        int base = part*32 + c;
        acc += pr[base]*w4.x + pr[128 + base]*w4.y + pr[256 + base]*w4.z + pr[384 + base]*w4.w;
    }
    red[tid] = acc;
    __syncthreads();
    if (tid < 64) {
        float s = red[tid*4] + red[tid*4+1] + red[tid*4+2] + red[tid*4+3] + bo[tid];
        float e = __expf(s);
        float u = 1.f + e, u2 = u*u;
        float msh = (s > 15.f) ? s : s * (u2 - 1.f) / (u2 + 1.f);
        float val = x[n*64 + tid] + msh;
        float m = val, m2 = val*val;
        #pragma unroll
        for (int off = 1; off < 64; off <<= 1) { m += __shfl_xor(m, off); m2 += __shfl_xor(m2, off); }
        m *= (1.f/64.f); m2 *= (1.f/64.f);
        float var = m2 - m*m;
        out[n*64 + tid] = (val - m) * rsqrtf(var + 1e-5f) * g[tid] + be[tid];
    }
}

extern "C" void kernel_launch(void* const* d_in, const int* in_sizes, int n_in,
                              void* d_out, int out_size, void* d_ws, size_t ws_size,
                              hipStream_t stream) {
    const float* q    = (const float*)d_in[0];
    const float* k    = (const float*)d_in[1];
    const float* v    = (const float*)d_in[2];
    const float* bias = (const float*)d_in[3];
    const float* Wq   = (const float*)d_in[4];
    const float* bq   = (const float*)d_in[5];
    const float* Wk   = (const float*)d_in[6];
    const float* bk   = (const float*)d_in[7];
    const float* Wqo  = (const float*)d_in[8];
    const float* bqo  = (const float*)d_in[9];
    const float* Wko  = (const float*)d_in[10];
    const float* bko  = (const float*)d_in[11];
    const float* qlg  = (const float*)d_in[12];
    const float* qlb  = (const float*)d_in[13];
    const float* klg  = (const float*)d_in[14];
    const float* klb  = (const float*)d_in[15];
    const float* Wb   = (const float*)d_in[16];
    const float* bb   = (const float*)d_in[17];
    const float* Wbo  = (const float*)d_in[18];
    const float* bbo  = (const float*)d_in[19];

    float* out = (float*)d_out;
    float* ws  = (float*)d_ws;
    float* diffs = ws;                                   // 4*262144 fp32 (also logits, in place)
    float* pq    = ws + 4*MROWS;                         // 262144
    float* pk    = pq + MROWS;                           // 262144
    unsigned short* wfrag = (unsigned short*)(pk + MROWS); // 131072 bf16 (frag1 | frag2)

    float* q_new = out;             // 512*64
    float* k_new = out + 32768;     // 512*64
    float* vmean = out + 65536;     // 512
    float* b_out = out + 66048;     // 512*512*128

    pre_kernel<<<dim3(1536), dim3(256), 0, stream>>>(q, k, Wq, bq, Wk, bk, pq, pk, Wb, Wbo, wfrag);
    bias_kernel<<<dim3(1024), dim3(256), 0, stream>>>(bias, wfrag, bb, wfrag + 65536, bbo, b_out, diffs);
    qk_kernel<<<dim3(256), dim3(256), 0, stream>>>(pq, pk, diffs);
    attnval_kernel<<<dim3(512), dim3(256), 0, stream>>>(diffs, v, vmean);
    qkout_kernel<<<dim3(512), dim3(256), 0, stream>>>(pq, q, Wqo, bqo, qlg, qlb, q_new);
    qkout_kernel<<<dim3(512), dim3(256), 0, stream>>>(pk, k, Wko, bko, klg, klb, k_new);
}